// Round 1
// baseline (565.346 us; speedup 1.0000x reference)
//
#include <hip/hip_runtime.h>
#include <hip/hip_bf16.h>

#define H 32
#define HKV 8
#define DD 128
#define SMAX 1024
#define QBLK 64
#define KVBLK 64
#define SCALE 0.08838834764831845f  // 1/sqrt(128)

typedef __attribute__((ext_vector_type(8))) short bf16x8;
typedef __attribute__((ext_vector_type(4))) float f32x4;
typedef __attribute__((ext_vector_type(4))) unsigned short u16x4;

__device__ inline unsigned short f2bf(float f) {
  unsigned u = __float_as_uint(f);
  unsigned r = 0x7fffu + ((u >> 16) & 1u);
  return (unsigned short)((u + r) >> 16);
}

__global__ __launch_bounds__(256) void fa_kernel(
    const float* __restrict__ q, const float* __restrict__ k,
    const float* __restrict__ v, const int* __restrict__ cu,
    float* __restrict__ out, int nqb) {
  const int bx = blockIdx.x;
  const int qb = bx % nqb;
  const int h  = (bx / nqb) % H;
  const int b  = bx / (nqb * H);
  const int kvh = h / (H / HKV);

  const int seq_start = cu[b];
  const int seq_len   = cu[b + 1] - seq_start;
  const int q_base = qb * QBLK;
  if (q_base >= seq_len) return;

  const int tid  = threadIdx.x;
  const int lane = tid & 63;
  const int w    = tid >> 6;     // wave 0..3
  const int lg   = lane >> 4;    // 16-lane group 0..3
  const int lr   = lane & 15;

  __shared__ __align__(16) char kbuf[KVBLK * DD * 2];      // [64][128] bf16, swizzled
  __shared__ __align__(16) char vbuf[DD * KVBLK * 2];      // [128][64] bf16 (V^T), swizzled
  __shared__ __align__(16) char pbuf[4 * 16 * KVBLK * 2];  // per-wave [16][64] bf16, swizzled

  // ---- Q fragments in registers: rows (w*16 + lr), 4 K-slices of 8 along D ----
  const int q_pos = q_base + w * 16 + lr;
  const int q_tok = seq_start + min(q_pos, seq_len - 1);
  bf16x8 qf[4];
  {
    const float* qp = q + (size_t)q_tok * (H * DD) + h * DD;
#pragma unroll
    for (int ks = 0; ks < 4; ++ks) {
      int d0 = 8 * lg + 32 * ks;
      float4 x = *(const float4*)(qp + d0);
      float4 y = *(const float4*)(qp + d0 + 4);
      bf16x8 t;
      t[0] = (short)f2bf(x.x); t[1] = (short)f2bf(x.y);
      t[2] = (short)f2bf(x.z); t[3] = (short)f2bf(x.w);
      t[4] = (short)f2bf(y.x); t[5] = (short)f2bf(y.y);
      t[6] = (short)f2bf(y.z); t[7] = (short)f2bf(y.w);
      qf[ks] = t;
    }
  }

  f32x4 o[8];
#pragma unroll
  for (int i = 0; i < 8; ++i) o[i] = (f32x4){0.f, 0.f, 0.f, 0.f};
  float m_run[4], l_run[4];
#pragma unroll
  for (int r = 0; r < 4; ++r) { m_run[r] = -1e30f; l_run[r] = 0.f; }

  char* pw = pbuf + w * (16 * KVBLK * 2);

  for (int t = 0; t <= qb; ++t) {
    __syncthreads();
    // ---- stage K[64][128] and V^T[128][64] as bf16 (XOR-swizzled rows) ----
#pragma unroll
    for (int i = 0; i < 8; ++i) {
      int f4  = i * 256 + tid;     // 0..2047 float4 slots
      int row = f4 >> 5;           // kv row in tile (128 floats = 32 f4/row)
      int c4  = f4 & 31;
      int tok = seq_start + min(t * KVBLK + row, seq_len - 1);
      const float* kp = k + (size_t)tok * (HKV * DD) + kvh * DD + c4 * 4;
      float4 kf = *(const float4*)kp;
      u16x4 hh;
      hh[0] = f2bf(kf.x); hh[1] = f2bf(kf.y); hh[2] = f2bf(kf.z); hh[3] = f2bf(kf.w);
      *(u16x4*)(kbuf + row * 256 + ((c4 * 8) ^ ((row & 7) << 4))) = hh;

      const float* vp = v + (size_t)tok * (HKV * DD) + kvh * DD + c4 * 4;
      float4 vf = *(const float4*)vp;
      unsigned short vb[4] = {f2bf(vf.x), f2bf(vf.y), f2bf(vf.z), f2bf(vf.w)};
      int dbase = c4 * 4;
#pragma unroll
      for (int j = 0; j < 4; ++j) {
        int dr = dbase + j;
        *(unsigned short*)(vbuf + dr * (KVBLK * 2) + ((row * 2) ^ ((dr & 7) << 4))) = vb[j];
      }
    }
    __syncthreads();

    // ---- QK^T: S[16 q][64 kv] per wave = 4 n-tiles x 4 K-slices ----
    f32x4 s[4];
#pragma unroll
    for (int n = 0; n < 4; ++n) {
      f32x4 acc = {0.f, 0.f, 0.f, 0.f};
      int kcol = n * 16 + lr;
#pragma unroll
      for (int ks = 0; ks < 4; ++ks) {
        int byte = (16 * lg + 64 * ks) ^ ((kcol & 7) << 4);
        bf16x8 kb = *(const bf16x8*)(kbuf + kcol * 256 + byte);
        acc = __builtin_amdgcn_mfma_f32_16x16x32_bf16(qf[ks], kb, acc, 0, 0, 0);
      }
      s[n] = acc;
    }

    // ---- scale + causal mask (diagonal tile only) ----
    const bool diag = (t == qb);
#pragma unroll
    for (int n = 0; n < 4; ++n) {
      int kv_pos = t * KVBLK + n * 16 + lr;
#pragma unroll
      for (int r = 0; r < 4; ++r) {
        float val = s[n][r] * SCALE;
        int qp_ = q_base + w * 16 + 4 * lg + r;
        if (diag && kv_pos > qp_) val = -1e30f;
        s[n][r] = val;
      }
    }

    // ---- online softmax: rows live in 16-lane groups, reg r = row (4*lg + r) ----
    float corr[4];
#pragma unroll
    for (int r = 0; r < 4; ++r) {
      float mx = fmaxf(fmaxf(s[0][r], s[1][r]), fmaxf(s[2][r], s[3][r]));
#pragma unroll
      for (int off = 1; off < 16; off <<= 1)
        mx = fmaxf(mx, __shfl_xor(mx, off, 64));
      float mn = fmaxf(m_run[r], mx);
      corr[r] = __expf(m_run[r] - mn);
      m_run[r] = mn;
    }
    float rsum[4] = {0.f, 0.f, 0.f, 0.f};
#pragma unroll
    for (int n = 0; n < 4; ++n) {
#pragma unroll
      for (int r = 0; r < 4; ++r) {
        float p = __expf(s[n][r] - m_run[r]);
        s[n][r] = p;
        rsum[r] += p;
      }
    }
#pragma unroll
    for (int r = 0; r < 4; ++r) {
      float rs = rsum[r];
#pragma unroll
      for (int off = 1; off < 16; off <<= 1)
        rs += __shfl_xor(rs, off, 64);
      l_run[r] = l_run[r] * corr[r] + rs;
    }
#pragma unroll
    for (int dt = 0; dt < 8; ++dt)
#pragma unroll
      for (int r = 0; r < 4; ++r) o[dt][r] *= corr[r];

    // ---- write P (bf16) to per-wave LDS tile, swizzled ----
#pragma unroll
    for (int n = 0; n < 4; ++n) {
#pragma unroll
      for (int r = 0; r < 4; ++r) {
        int prow = 4 * lg + r;
        int pcol = n * 16 + lr;
        *(unsigned short*)(pw + prow * (KVBLK * 2) + ((pcol * 2) ^ ((prow & 7) << 4))) =
            f2bf(s[n][r]);
      }
    }

    // ---- PV: O[16 q][128 d] += P[16][64] * V[64][128] ----
#pragma unroll
    for (int ks = 0; ks < 2; ++ks) {
      int pbyte = (16 * lg + 64 * ks) ^ ((lr & 7) << 4);
      bf16x8 pa = *(const bf16x8*)(pw + lr * (KVBLK * 2) + pbyte);
#pragma unroll
      for (int dt = 0; dt < 8; ++dt) {
        int drow = dt * 16 + lr;
        int vbyte = (16 * lg + 64 * ks) ^ ((drow & 7) << 4);
        bf16x8 vb = *(const bf16x8*)(vbuf + drow * (KVBLK * 2) + vbyte);
        o[dt] = __builtin_amdgcn_mfma_f32_16x16x32_bf16(pa, vb, o[dt], 0, 0, 0);
      }
    }
  }

  // ---- epilogue: O / l, store fp32 ----
  float inv_l[4];
#pragma unroll
  for (int r = 0; r < 4; ++r) inv_l[r] = 1.0f / l_run[r];
#pragma unroll
  for (int r = 0; r < 4; ++r) {
    int qp_ = q_base + w * 16 + 4 * lg + r;
    if (qp_ < seq_len) {
      float* op = out + (size_t)(seq_start + qp_) * (H * DD) + h * DD + lr;
#pragma unroll
      for (int dt = 0; dt < 8; ++dt) op[dt * 16] = o[dt][r] * inv_l[r];
    }
  }
}

extern "C" void kernel_launch(void* const* d_in, const int* in_sizes, int n_in,
                              void* d_out, int out_size, void* d_ws, size_t ws_size,
                              hipStream_t stream) {
  const float* q = (const float*)d_in[0];
  const float* k = (const float*)d_in[1];
  const float* v = (const float*)d_in[2];
  const int* cu  = (const int*)d_in[3];
  float* out = (float*)d_out;
  const int B = in_sizes[3] - 1;     // 4
  const int nqb = SMAX / QBLK;       // 16
  dim3 grid(B * H * nqb);
  fa_kernel<<<grid, 256, 0, stream>>>(q, k, v, cu, out, nqb);
}

// Round 2
// 423.950 us; speedup vs baseline: 1.3335x; 1.3335x over previous
//
#include <hip/hip_runtime.h>
#include <hip/hip_bf16.h>

#define H 32
#define HKV 8
#define DD 128
#define SMAX 1024
#define QBLK 32            // q rows per wave (per head)
#define KVBLK 64
#define NQB (SMAX / QBLK)  // 32
#define SCALE 0.08838834764831845f  // 1/sqrt(128)

typedef __attribute__((ext_vector_type(8))) short bf16x8;
typedef __attribute__((ext_vector_type(4))) short bf16x4;
typedef __attribute__((ext_vector_type(4))) float f32x4;
typedef __attribute__((ext_vector_type(4))) unsigned short u16x4;

__device__ inline unsigned short f2bf(float f) {
  unsigned u = __float_as_uint(f);
  unsigned r = 0x7fffu + ((u >> 16) & 1u);
  return (unsigned short)((u + r) >> 16);
}

// V^T swizzle: bits 3..6 vary with d -> 16 distinct 8B slots per 16-lane
// quarter-wave (consecutive d). Writes are 2B/8B (bits 0..2 untouched),
// reads are ds_read_b64 pairs (8B, bit-3 XOR legal).
__device__ inline int swzV(int d) {
  return ((d & 7) << 4) | (((d >> 3) & 1) << 3);
}

__global__ __launch_bounds__(256) void fa_kernel(
    const float* __restrict__ q, const float* __restrict__ k,
    const float* __restrict__ v, const int* __restrict__ cu,
    float* __restrict__ out, int inner_n) {
  const int bx = blockIdx.x;
  const int inner = bx % inner_n;
  const int qb = NQB - 1 - (bx / inner_n);  // big q-blocks dispatch first
  const int b = inner / HKV;
  const int kvh = inner % HKV;

  const int seq_start = cu[b];
  const int seq_len = cu[b + 1] - seq_start;
  if (qb * QBLK >= seq_len) return;

  const int tid = threadIdx.x;
  const int lane = tid & 63;
  const int w = tid >> 6;
  const int lg = lane >> 4;
  const int lr = lane & 15;
  const int h = kvh * (H / HKV) + w;  // wave w owns head kvh*4+w

  __shared__ __align__(16) char kbuf[KVBLK * DD * 2];  // [64 kv][128 d] bf16
  __shared__ __align__(16) char vbuf[DD * KVBLK * 2];  // [128 d][64 kv] bf16 (V^T)
  __shared__ __align__(16) char pbuf[4 * QBLK * KVBLK * 2];  // per-wave [32][64]

  // ---- Q fragments: 2 m-tiles x 4 K-slices; row = lr, k = 8*lg+32*ks+[0..7] ----
  bf16x8 qf[2][4];
#pragma unroll
  for (int m = 0; m < 2; ++m) {
    int q_pos = qb * QBLK + m * 16 + lr;
    int q_tok = seq_start + min(q_pos, seq_len - 1);
    const float* qp = q + (size_t)q_tok * (H * DD) + h * DD;
#pragma unroll
    for (int ks = 0; ks < 4; ++ks) {
      int d0 = 8 * lg + 32 * ks;
      float4 x = *(const float4*)(qp + d0);
      float4 y = *(const float4*)(qp + d0 + 4);
      bf16x8 t;
      t[0] = (short)f2bf(x.x); t[1] = (short)f2bf(x.y);
      t[2] = (short)f2bf(x.z); t[3] = (short)f2bf(x.w);
      t[4] = (short)f2bf(y.x); t[5] = (short)f2bf(y.y);
      t[6] = (short)f2bf(y.z); t[7] = (short)f2bf(y.w);
      qf[m][ks] = t;
    }
  }

  f32x4 o[2][8];
#pragma unroll
  for (int m = 0; m < 2; ++m)
#pragma unroll
    for (int i = 0; i < 8; ++i) o[m][i] = (f32x4){0.f, 0.f, 0.f, 0.f};
  float m_run[2][4], l_run[2][4];
#pragma unroll
  for (int m = 0; m < 2; ++m)
#pragma unroll
    for (int r = 0; r < 4; ++r) { m_run[m][r] = -1e30f; l_run[m][r] = 0.f; }

  char* pw = pbuf + w * (QBLK * KVBLK * 2);
  const int qmax = qb * QBLK + QBLK - 1;
  const int tmax = qmax >> 6;

  for (int t = 0; t <= tmax; ++t) {
    __syncthreads();
    // ---- stage K[64][128] and V^T[128][64] as bf16 (once for 4 heads) ----
#pragma unroll
    for (int i = 0; i < 8; ++i) {
      int f4 = i * 256 + tid;
      int row = f4 >> 5;
      int c4 = f4 & 31;
      int tok = seq_start + min(t * KVBLK + row, seq_len - 1);
      const float* kp = k + (size_t)tok * (HKV * DD) + kvh * DD + c4 * 4;
      float4 kf = *(const float4*)kp;
      u16x4 hh;
      hh[0] = f2bf(kf.x); hh[1] = f2bf(kf.y); hh[2] = f2bf(kf.z); hh[3] = f2bf(kf.w);
      *(u16x4*)(kbuf + row * 256 + ((c4 * 8) ^ ((row & 7) << 4))) = hh;

      const float* vp = v + (size_t)tok * (HKV * DD) + kvh * DD + c4 * 4;
      float4 vf = *(const float4*)vp;
      unsigned short vb_[4] = {f2bf(vf.x), f2bf(vf.y), f2bf(vf.z), f2bf(vf.w)};
#pragma unroll
      for (int j = 0; j < 4; ++j) {
        int d = 4 * c4 + j;
        *(unsigned short*)(vbuf + d * 128 + ((row * 2) ^ swzV(d))) = vb_[j];
      }
    }
    __syncthreads();

    // ---- QK^T: S[32 q][64 kv] per wave; skip n-tiles above causal line ----
    f32x4 s[2][4];
    __builtin_amdgcn_s_setprio(1);
#pragma unroll
    for (int n = 0; n < 4; ++n) {
      if (t * 64 + n * 16 <= qmax) {
        int kcol = n * 16 + lr;
        bf16x8 kb[4];
#pragma unroll
        for (int ks = 0; ks < 4; ++ks)
          kb[ks] = *(const bf16x8*)(kbuf + kcol * 256 +
                                    ((16 * lg + 64 * ks) ^ ((kcol & 7) << 4)));
#pragma unroll
        for (int m = 0; m < 2; ++m) {
          f32x4 acc = {0.f, 0.f, 0.f, 0.f};
#pragma unroll
          for (int ks = 0; ks < 4; ++ks)
            acc = __builtin_amdgcn_mfma_f32_16x16x32_bf16(qf[m][ks], kb[ks], acc, 0, 0, 0);
          s[m][n] = acc;
        }
      } else {
#pragma unroll
        for (int m = 0; m < 2; ++m) s[m][n] = (f32x4){-2e30f, -2e30f, -2e30f, -2e30f};
      }
    }
    __builtin_amdgcn_s_setprio(0);

    // ---- scale + causal mask (diagonal tile only) ----
    const bool diag = (t == tmax);
#pragma unroll
    for (int n = 0; n < 4; ++n) {
      if (t * 64 + n * 16 <= qmax) {
        int kv_pos = t * 64 + n * 16 + lr;
#pragma unroll
        for (int m = 0; m < 2; ++m) {
          int qp_ = qb * QBLK + m * 16 + 4 * lg;
#pragma unroll
          for (int r = 0; r < 4; ++r) {
            float val = s[m][n][r] * SCALE;
            if (diag && kv_pos > qp_ + r) val = -1e30f;
            s[m][n][r] = val;
          }
        }
      }
    }

    // ---- online softmax (rows live across lr within each lg group) ----
#pragma unroll
    for (int m = 0; m < 2; ++m) {
      float corr[4];
#pragma unroll
      for (int r = 0; r < 4; ++r) {
        float mx = fmaxf(fmaxf(s[m][0][r], s[m][1][r]), fmaxf(s[m][2][r], s[m][3][r]));
#pragma unroll
        for (int off = 1; off < 16; off <<= 1)
          mx = fmaxf(mx, __shfl_xor(mx, off, 64));
        float mn = fmaxf(m_run[m][r], mx);
        corr[r] = __expf(m_run[m][r] - mn);
        m_run[m][r] = mn;
      }
      float rsum[4] = {0.f, 0.f, 0.f, 0.f};
#pragma unroll
      for (int n = 0; n < 4; ++n) {
#pragma unroll
        for (int r = 0; r < 4; ++r) {
          float p = __expf(s[m][n][r] - m_run[m][r]);
          s[m][n][r] = p;
          rsum[r] += p;
        }
      }
#pragma unroll
      for (int r = 0; r < 4; ++r) {
        float rs = rsum[r];
#pragma unroll
        for (int off = 1; off < 16; off <<= 1)
          rs += __shfl_xor(rs, off, 64);
        l_run[m][r] = l_run[m][r] * corr[r] + rs;
      }
#pragma unroll
      for (int dt = 0; dt < 8; ++dt)
#pragma unroll
        for (int r = 0; r < 4; ++r) o[m][dt][r] *= corr[r];

      // ---- write P tile rows [16m, 16m+16) ----
#pragma unroll
      for (int n = 0; n < 4; ++n) {
#pragma unroll
        for (int r = 0; r < 4; ++r) {
          int prow = m * 16 + 4 * lg + r;
          int pcol = n * 16 + lr;
          *(unsigned short*)(pw + prow * 128 + ((pcol * 2) ^ ((prow & 7) << 4))) =
              f2bf(s[m][n][r]);
        }
      }
    }

    // ---- PV: O[32 q][128 d] += P[32][64] * V[64][128]; skip dead upper half ----
    const int nks = (t * 64 + 32 <= qmax) ? 2 : 1;
    __builtin_amdgcn_s_setprio(1);
    for (int ks = 0; ks < nks; ++ks) {
      bf16x8 pa[2];
#pragma unroll
      for (int m = 0; m < 2; ++m)
        pa[m] = *(const bf16x8*)(pw + (m * 16 + lr) * 128 +
                                 ((16 * lg + 64 * ks) ^ ((lr & 7) << 4)));
#pragma unroll
      for (int dt = 0; dt < 8; ++dt) {
        int d = dt * 16 + lr;
        int addrA = d * 128 + ((16 * lg + 64 * ks) ^ swzV(d));
        bf16x4 lo = *(const bf16x4*)(vbuf + addrA);
        bf16x4 hi = *(const bf16x4*)(vbuf + (addrA ^ 8));
        bf16x8 vbf;
        vbf[0] = lo[0]; vbf[1] = lo[1]; vbf[2] = lo[2]; vbf[3] = lo[3];
        vbf[4] = hi[0]; vbf[5] = hi[1]; vbf[6] = hi[2]; vbf[7] = hi[3];
#pragma unroll
        for (int m = 0; m < 2; ++m)
          o[m][dt] = __builtin_amdgcn_mfma_f32_16x16x32_bf16(pa[m], vbf, o[m][dt], 0, 0, 0);
      }
    }
    __builtin_amdgcn_s_setprio(0);
  }

  // ---- epilogue ----
#pragma unroll
  for (int m = 0; m < 2; ++m) {
#pragma unroll
    for (int r = 0; r < 4; ++r) {
      int qp_ = qb * QBLK + m * 16 + 4 * lg + r;
      if (qp_ < seq_len) {
        float inv_l = 1.0f / l_run[m][r];
        float* op = out + (size_t)(seq_start + qp_) * (H * DD) + h * DD + lr;
#pragma unroll
        for (int dt = 0; dt < 8; ++dt) op[dt * 16] = o[m][dt][r] * inv_l;
      }
    }
  }
}

extern "C" void kernel_launch(void* const* d_in, const int* in_sizes, int n_in,
                              void* d_out, int out_size, void* d_ws, size_t ws_size,
                              hipStream_t stream) {
  const float* q = (const float*)d_in[0];
  const float* k = (const float*)d_in[1];
  const float* v = (const float*)d_in[2];
  const int* cu = (const int*)d_in[3];
  float* out = (float*)d_out;
  const int B = in_sizes[3] - 1;  // 4
  const int inner_n = B * HKV;    // 32
  dim3 grid(NQB * inner_n);       // 1024 blocks, qb descending-major
  fa_kernel<<<grid, 256, 0, stream>>>(q, k, v, cu, out, inner_n);
}